// Round 4
// baseline (47.963 us; speedup 1.0000x reference)
//
#include <hip/hip_runtime.h>
#include <cstddef>

// Problem constants (from reference): B=4, N=4096, D=128, R=4, K=16, O=128
namespace {
constexpr int B_ = 4, N_ = 4096, D_ = 128, R_ = 4, K_ = 16, O_ = 128;
constexpr int NP1 = N_ + 1;            // padded table rows (row 0 = zeros)
constexpr int TN = 16;                 // nodes per block (MFMA M)
constexpr int THREADS = 256;
constexpr int KK = (R_ + 1) * D_;      // 640 stacked-K (4 relations + self)
constexpr int PITCH_A = KK + 8;        // 648 bf16 rows
}

typedef __bf16 bf16x8 __attribute__((ext_vector_type(8)));
typedef __bf16 bf16x4 __attribute__((ext_vector_type(4)));
typedef __bf16 bf16x2 __attribute__((ext_vector_type(2)));
typedef float  f32x4v __attribute__((ext_vector_type(4)));
using u32 = unsigned int;

// ---- prep 1: fp32 features -> bf16 padded table ws[B][NP1][D], row 0 = 0 ----
__global__ __launch_bounds__(256)
void prep_table(const float* __restrict__ nf, __bf16* __restrict__ ptab) {
    const int c = blockIdx.x * 256 + threadIdx.x;        // one bf16x4 chunk
    const int total = B_ * NP1 * (D_ / 4);
    if (c >= total) return;
    const int b   = c / (NP1 * 32);
    const int rem = c % (NP1 * 32);
    const int row = rem >> 5;
    const int q   = rem & 31;
    bf16x4 res;
    if (row == 0) {
        res[0] = (__bf16)0.f; res[1] = (__bf16)0.f;
        res[2] = (__bf16)0.f; res[3] = (__bf16)0.f;
    } else {
        const float4 v = *(const float4*)(nf + ((size_t)b * N_ + (row - 1)) * D_ + q * 4);
        res[0] = (__bf16)v.x; res[1] = (__bf16)v.y;
        res[2] = (__bf16)v.z; res[3] = (__bf16)v.w;
    }
    *(bf16x4*)(ptab + ((size_t)b * NP1 + row) * D_ + q * 4) = res;
}

// ---- prep 2: stacked W [640][128] -> transposed bf16 Wt[128][640] ----
__global__ __launch_bounds__(256)
void prep_wt(const float* __restrict__ relk, const float* __restrict__ selfk,
             __bf16* __restrict__ wt) {
    const int t = blockIdx.x * 256 + threadIdx.x;
    if (t >= O_ * KK) return;
    const int o  = t / KK;
    const int kk = t % KK;
    const float w = (kk < R_ * D_) ? relk[(size_t)kk * O_ + o]
                                   : selfk[(size_t)(kk - R_ * D_) * O_ + o];
    wt[(size_t)o * KK + kk] = (__bf16)w;
}

// ---- main: SGPR-scalarized gather+mean then MFMA matmul ----
__global__ __launch_bounds__(THREADS, 4)
void gcn_fused(const __bf16* __restrict__ ptab,  // [B][NP1][D] bf16, row0=0
               const int*    __restrict__ nbr,   // [B][R][N][K]
               const __bf16* __restrict__ wt,    // [O][KK] bf16 (W^T stacked)
               const float*  __restrict__ bias,  // [O]
               float*        __restrict__ out)   // [B][N][O]
{
    __shared__ __bf16 agg[TN][PITCH_A];          // 16 x 648 bf16 = 20736 B

    // batch<->XCD affinity: XCD pair {2b,2b+1} serves batch b only (gather
    // working set = one 1.05 MB bf16 table -> L2-resident; verified r2:
    // FETCH_SIZE 158 MB -> 6.8 MB).
    const int hw   = blockIdx.x;
    const int xcd  = hw & 7;
    const int b    = xcd >> 1;
    const int tile = (xcd & 1) + ((hw >> 3) << 1);   // 0..255 within batch
    const int n0   = tile * TN;

    const int tid = threadIdx.x;
    const int wv  = tid >> 6;            // wave id = relation r
    const int l   = tid & 63;            // lane: owns elements 2l, 2l+1 of a row

    // ---- Phase 1: gather + mean. Wave wv handles relation wv, all 16 nodes.
    // Indices go VGPR->SGPR via readfirstlane; each gather is then
    // global_load_dword v, v_laneoff, s[base] with the base computed on the
    // scalar ALU. No shuffles, no per-load VALU address math. Next node's
    // indices prefetched (branchless clamp) while current gathers fly.
    {
        const int* ib = nbr + (((size_t)b * R_ + wv) * N_ + n0) * K_;  // 256 ints
        const __bf16* __restrict__ tb = ptab + (size_t)b * NP1 * D_;

        int4 q0 = ((const int4*)ib)[0];
        int4 q1 = ((const int4*)ib)[1];
        int4 q2 = ((const int4*)ib)[2];
        int4 q3 = ((const int4*)ib)[3];

        #pragma unroll 2
        for (int n = 0; n < TN; ++n) {
            int sidx[16];
            sidx[0]  = __builtin_amdgcn_readfirstlane(q0.x);
            sidx[1]  = __builtin_amdgcn_readfirstlane(q0.y);
            sidx[2]  = __builtin_amdgcn_readfirstlane(q0.z);
            sidx[3]  = __builtin_amdgcn_readfirstlane(q0.w);
            sidx[4]  = __builtin_amdgcn_readfirstlane(q1.x);
            sidx[5]  = __builtin_amdgcn_readfirstlane(q1.y);
            sidx[6]  = __builtin_amdgcn_readfirstlane(q1.z);
            sidx[7]  = __builtin_amdgcn_readfirstlane(q1.w);
            sidx[8]  = __builtin_amdgcn_readfirstlane(q2.x);
            sidx[9]  = __builtin_amdgcn_readfirstlane(q2.y);
            sidx[10] = __builtin_amdgcn_readfirstlane(q2.z);
            sidx[11] = __builtin_amdgcn_readfirstlane(q2.w);
            sidx[12] = __builtin_amdgcn_readfirstlane(q3.x);
            sidx[13] = __builtin_amdgcn_readfirstlane(q3.y);
            sidx[14] = __builtin_amdgcn_readfirstlane(q3.z);
            sidx[15] = __builtin_amdgcn_readfirstlane(q3.w);

            // branchless prefetch of next node's 16 indices
            const int np = (n + 1 < TN) ? (n + 1) : (TN - 1);
            const int4* nx = (const int4*)(ib + np * K_);
            q0 = nx[0]; q1 = nx[1]; q2 = nx[2]; q3 = nx[3];

            float al0 = 0.f, ah0 = 0.f, al1 = 0.f, ah1 = 0.f;
            #pragma unroll
            for (int k = 0; k < K_; ++k) {
                const u32 u = *((const u32*)(tb + (size_t)sidx[k] * D_) + l);
                const float lo = __uint_as_float(u << 16);
                const float hi = __uint_as_float(u & 0xffff0000u);
                if (k & 1) { al1 += lo; ah1 += hi; }
                else       { al0 += lo; ah0 += hi; }
            }
            bf16x2 res;
            res[0] = (__bf16)((al0 + al1) * 0.0625f);
            res[1] = (__bf16)((ah0 + ah1) * 0.0625f);
            *(bf16x2*)&agg[n][wv * D_ + l * 2] = res;
        }

        // self features: wave wv copies rows wv*4 .. wv*4+3 (bitwise bf16 copy)
        #pragma unroll
        for (int j = 0; j < 4; ++j) {
            const int n = wv * 4 + j;
            const u32 u = *((const u32*)(ptab + ((size_t)b * NP1 + n0 + n + 1) * D_) + l);
            *((u32*)&agg[n][R_ * D_] + l) = u;
        }
    }
    __syncthreads();

    // ---- Phase 2: MFMA. Per wave: 16x32 output (2 col-tiles), K = 640. ----
    const int lr = l & 15;               // A row / B col / C col
    const int lk = l >> 4;               // k-group
    const int ct0 = wv * 2, ct1 = wv * 2 + 1;

    const __bf16* __restrict__ wr0 = wt + (size_t)(ct0 * 16 + lr) * KK + lk * 8;
    const __bf16* __restrict__ wr1 = wt + (size_t)(ct1 * 16 + lr) * KK + lk * 8;
    const __bf16* arow = &agg[lr][lk * 8];

    f32x4v acc0 = {0.f, 0.f, 0.f, 0.f};
    f32x4v acc1 = {0.f, 0.f, 0.f, 0.f};
    #pragma unroll 4
    for (int k0 = 0; k0 < KK; k0 += 32) {
        const bf16x8 a  = *(const bf16x8*)(arow + k0);   // ds_read_b128
        const bf16x8 b0 = *(const bf16x8*)(wr0 + k0);    // global b128, L2-hit
        const bf16x8 b1 = *(const bf16x8*)(wr1 + k0);
        acc0 = __builtin_amdgcn_mfma_f32_16x16x32_bf16(a, b0, acc0, 0, 0, 0);
        acc1 = __builtin_amdgcn_mfma_f32_16x16x32_bf16(a, b1, acc1, 0, 0, 0);
    }

    const float bv0 = bias[ct0 * 16 + lr];
    const float bv1 = bias[ct1 * 16 + lr];
    #pragma unroll
    for (int j = 0; j < 4; ++j) {
        const int row = lk * 4 + j;      // node within tile
        float* op = out + ((size_t)b * N_ + n0 + row) * O_;
        op[ct0 * 16 + lr] = fmaxf(acc0[j] + bv0, 0.f);
        op[ct1 * 16 + lr] = fmaxf(acc1[j] + bv1, 0.f);
    }
}

extern "C" void kernel_launch(void* const* d_in, const int* in_sizes, int n_in,
                              void* d_out, int out_size, void* d_ws, size_t ws_size,
                              hipStream_t stream) {
    const float* nf    = (const float*)d_in[0];  // node_features  [B,N,D] f32
    const int*   nbr   = (const int*)  d_in[1];  // neighbor_indices [B,R,N,K] i32
    const float* relk  = (const float*)d_in[2];  // relation_kernels [R,D,O] f32
    const float* selfk = (const float*)d_in[3];  // self_kernel [D,O] f32
    const float* bias  = (const float*)d_in[4];  // bias [O] f32
    float* outp = (float*)d_out;                 // [B,N,O] f32

    // workspace layout: bf16 padded table, then bf16 W^T
    __bf16* ptab = (__bf16*)d_ws;                              // B*NP1*D*2 = 4,195,328 B
    __bf16* wtp  = (__bf16*)((char*)d_ws + (size_t)B_ * NP1 * D_ * 2);  // 163,840 B

    {
        const int total = B_ * NP1 * (D_ / 4);
        prep_table<<<(total + 255) / 256, 256, 0, stream>>>(nf, ptab);
    }
    prep_wt<<<(O_ * KK + 255) / 256, 256, 0, stream>>>(relk, selfk, wtp);

    dim3 grid(B_ * (N_ / TN));
    gcn_fused<<<grid, THREADS, 0, stream>>>(ptab, nbr, wtp, bias, outp);
}

// Round 5
// 39.209 us; speedup vs baseline: 1.2233x; 1.2233x over previous
//
#include <hip/hip_runtime.h>
#include <cstddef>

// Problem constants (from reference): B=4, N=4096, D=128, R=4, K=16, O=128
namespace {
constexpr int B_ = 4, N_ = 4096, D_ = 128, R_ = 4, K_ = 16, O_ = 128;
constexpr int NP1 = N_ + 1;            // padded table rows (row 0 = zeros)
constexpr int TN = 16;                 // nodes per block (MFMA M)
constexpr int THREADS = 512;           // 8 waves: wave = (relation, node-half)
constexpr int KK = (R_ + 1) * D_;      // 640 stacked-K (4 relations + self)
constexpr int PITCH_A = KK + 8;        // 648 bf16 per row
}

typedef __bf16 bf16x8 __attribute__((ext_vector_type(8)));
typedef __bf16 bf16x4 __attribute__((ext_vector_type(4)));
typedef __bf16 bf16x2 __attribute__((ext_vector_type(2)));
typedef float  f32x4v __attribute__((ext_vector_type(4)));
using u32 = unsigned int;

// ---- prep (fused): bf16 padded table + transposed bf16 W^T ----
// part A: ptab[B][NP1][D], row 0 = zeros, row i+1 = features of node i
// part B: wt[O][KK], wt[o][kk] = stackedW[kk][o]
__global__ __launch_bounds__(256)
void prep_all(const float* __restrict__ nf, const float* __restrict__ relk,
              const float* __restrict__ selfk,
              __bf16* __restrict__ ptab, __bf16* __restrict__ wt) {
    int t = blockIdx.x * 256 + threadIdx.x;
    const int total_tab = B_ * NP1 * (D_ / 4);          // bf16x4 chunks
    if (t < total_tab) {
        const int b   = t / (NP1 * 32);
        const int rem = t % (NP1 * 32);
        const int row = rem >> 5;
        const int q   = rem & 31;
        bf16x4 res;
        if (row == 0) {
            res[0] = (__bf16)0.f; res[1] = (__bf16)0.f;
            res[2] = (__bf16)0.f; res[3] = (__bf16)0.f;
        } else {
            const float4 v = *(const float4*)(nf + ((size_t)b * N_ + (row - 1)) * D_ + q * 4);
            res[0] = (__bf16)v.x; res[1] = (__bf16)v.y;
            res[2] = (__bf16)v.z; res[3] = (__bf16)v.w;
        }
        *(bf16x4*)(ptab + ((size_t)b * NP1 + row) * D_ + q * 4) = res;
        return;
    }
    t -= total_tab;
    if (t < O_ * (KK / 4)) {
        const int o   = t / (KK / 4);
        const int kk  = (t % (KK / 4)) * 4;
        bf16x4 res;
        #pragma unroll
        for (int i = 0; i < 4; ++i) {
            const int kki = kk + i;
            const float w = (kki < R_ * D_) ? relk[(size_t)kki * O_ + o]
                                            : selfk[(size_t)(kki - R_ * D_) * O_ + o];
            res[i] = (__bf16)w;
        }
        *(bf16x4*)(wt + (size_t)o * KK + kk) = res;
    }
}

// ---- main: gather+mean (8 gather-waves/block) then MFMA matmul ----
__global__ __launch_bounds__(THREADS, 8)
void gcn_fused(const __bf16* __restrict__ ptab,  // [B][NP1][D] bf16, row0=0
               const int*    __restrict__ nbr,   // [B][R][N][K]
               const __bf16* __restrict__ wt,    // [O][KK] bf16 (W^T stacked)
               const float*  __restrict__ bias,  // [O]
               float*        __restrict__ out)   // [B][N][O]
{
    __shared__ __bf16 agg[TN][PITCH_A];          // 16 x 648 bf16 = 20736 B

    // batch<->XCD affinity: XCD pair {2b,2b+1} serves batch b only (gather
    // working set = one 1.05 MB bf16 table -> L2-resident; verified r2:
    // FETCH_SIZE 158 MB -> 6.8 MB).
    const int hw   = blockIdx.x;
    const int xcd  = hw & 7;
    const int b    = xcd >> 1;
    const int tile = (xcd & 1) + ((hw >> 3) << 1);   // 0..255 within batch
    const int n0   = tile * TN;

    const int tid = threadIdx.x;
    const int wv  = tid >> 6;            // 0..7: relation = wv&3, node-half = wv>>2
    const int l   = tid & 63;            // lane: owns bf16 elements 2l, 2l+1 of a row

    // ---- Phase 1: gather + mean. Wave wv: relation wv&3, nodes nb..nb+7. ----
    // Index base is wave-uniform (readfirstlane) -> compiler can scalarize the
    // 16 idx loads (s_load) and form SGPR row bases; each gather is then one
    // global_load_dword (64 lanes x 4B = full 256B bf16 row).
    {
        const int r  = wv & 3;
        const int nb = (wv >> 2) * 8;
        const int ioff = __builtin_amdgcn_readfirstlane(
            (((b * R_ + r) * N_) + n0 + nb) * K_);
        const int* __restrict__ ib = nbr + ioff;
        const __bf16* __restrict__ tb = ptab + (size_t)b * NP1 * D_;

        #pragma unroll 2
        for (int n = 0; n < 8; ++n) {
            int sidx[K_];
            #pragma unroll
            for (int k = 0; k < K_; ++k) sidx[k] = ib[n * K_ + k];

            float acl[4] = {0.f, 0.f, 0.f, 0.f};
            float ach[4] = {0.f, 0.f, 0.f, 0.f};
            #pragma unroll
            for (int k = 0; k < K_; ++k) {
                const u32 u = *((const u32*)(tb + (size_t)sidx[k] * D_) + l);
                acl[k & 3] += __uint_as_float(u << 16);
                ach[k & 3] += __uint_as_float(u & 0xffff0000u);
            }
            const float lo = (acl[0] + acl[1]) + (acl[2] + acl[3]);
            const float hi = (ach[0] + ach[1]) + (ach[2] + ach[3]);
            bf16x2 res;
            res[0] = (__bf16)(lo * 0.0625f);
            res[1] = (__bf16)(hi * 0.0625f);
            *(bf16x2*)&agg[nb + n][r * D_ + l * 2] = res;
        }

        // self features: wave wv copies rows 2wv, 2wv+1 (bitwise bf16 copy)
        #pragma unroll
        for (int j = 0; j < 2; ++j) {
            const int n = wv * 2 + j;
            const u32 u = *((const u32*)(ptab + ((size_t)b * NP1 + n0 + n + 1) * D_) + l);
            *((u32*)&agg[n][R_ * D_] + l) = u;
        }
    }
    __syncthreads();

    // ---- Phase 2: MFMA. Wave wv owns col-tile wv: 16x16 output, K = 640. ----
    const int lr = l & 15;               // A row / B col / C col
    const int lk = l >> 4;               // k-group
    const int ct = wv;                   // 0..7

    const __bf16* __restrict__ wr = wt + (size_t)(ct * 16 + lr) * KK + lk * 8;
    const __bf16* arow = &agg[lr][lk * 8];

    f32x4v acc = {0.f, 0.f, 0.f, 0.f};
    #pragma unroll 5
    for (int k0 = 0; k0 < KK; k0 += 32) {
        const bf16x8 a  = *(const bf16x8*)(arow + k0);   // ds_read_b128
        const bf16x8 bf = *(const bf16x8*)(wr + k0);     // global b128, L2-hit
        acc = __builtin_amdgcn_mfma_f32_16x16x32_bf16(a, bf, acc, 0, 0, 0);
    }

    const float bv = bias[ct * 16 + lr];
    #pragma unroll
    for (int j = 0; j < 4; ++j) {
        const int row = lk * 4 + j;      // node within tile
        out[((size_t)b * N_ + n0 + row) * O_ + ct * 16 + lr] = fmaxf(acc[j] + bv, 0.f);
    }
}

extern "C" void kernel_launch(void* const* d_in, const int* in_sizes, int n_in,
                              void* d_out, int out_size, void* d_ws, size_t ws_size,
                              hipStream_t stream) {
    const float* nf    = (const float*)d_in[0];  // node_features  [B,N,D] f32
    const int*   nbr   = (const int*)  d_in[1];  // neighbor_indices [B,R,N,K] i32
    const float* relk  = (const float*)d_in[2];  // relation_kernels [R,D,O] f32
    const float* selfk = (const float*)d_in[3];  // self_kernel [D,O] f32
    const float* bias  = (const float*)d_in[4];  // bias [O] f32
    float* outp = (float*)d_out;                 // [B,N,O] f32

    // workspace layout: bf16 padded table, then bf16 W^T
    __bf16* ptab = (__bf16*)d_ws;                              // B*NP1*D*2 = 4,195,328 B
    __bf16* wtp  = (__bf16*)((char*)d_ws + (size_t)B_ * NP1 * D_ * 2);  // 163,840 B

    {
        const int total = B_ * NP1 * (D_ / 4) + O_ * (KK / 4);
        prep_all<<<(total + 255) / 256, 256, 0, stream>>>(nf, relk, selfk, ptab, wtp);
    }

    dim3 grid(B_ * (N_ / TN));
    gcn_fused<<<grid, THREADS, 0, stream>>>(ptab, nbr, wtp, bias, outp);
}